// Round 12
// baseline (563.227 us; speedup 1.0000x reference)
//
#include <hip/hip_runtime.h>
#include <hip/hip_cooperative_groups.h>

namespace cg = cooperative_groups;

#define N_NODES   100000
#define N_EDGES   3200000
#define N_GRAPHS  1000
#define FEAT      512
#define EMB       7
#define HP        8      // padded per-node feature stride
#define N_CLASSES 10

#define GRID      512    // partition blocks; co-resident (2/CU, LDS allows 4)
#define BSH       8      // 256 nodes per bucket
#define DMASK     255
#define NBUCK     391    // ceil(100000/256)
#define TILE_A    6250   // 512*6250 == 3.2M exactly
#define SEGCAP    9216   // mean 8192, +11 sigma

union SMemU {
    int bins[NBUCK];                                     // P1 bucket hist
    struct { int pair[256]; int wsum[4]; int bkv; } sc;  // P2 scans
    int cur[NBUCK];                                      // P3 cursors
    struct { int stage[SEGCAP]; int bin[256]; int loff[256];
             int curs[256]; int tmp[256]; } gg;          // P4+P5 (40 KB)
    struct { float sred[4][EMB]; int bflag; } pool;      // P6
};

__device__ __forceinline__ int load_idx(const void* p, long long i, int is32) {
    if (is32) return ((const int*)p)[i];
    return (int)((const long long*)p)[i];
}

// matmul tile: h[n] = x[n] @ W_in (UNSCALED), 256 nodes, 1 node/thread
__device__ void mm_span(int nbase, const float* __restrict__ x,
                        const float* __restrict__ W, float* __restrict__ h) {
    int n = nbase + (int)threadIdx.x;
    if (n >= N_NODES) return;
    const float4* xr = (const float4*)(x + (size_t)n * FEAT);
    float acc[EMB];
#pragma unroll
    for (int j = 0; j < EMB; ++j) acc[j] = 0.0f;
#pragma unroll 4
    for (int k4 = 0; k4 < FEAT / 4; ++k4) {
        float4 v = xr[k4];
        const float* w = W + k4 * 4 * EMB;
#pragma unroll
        for (int j = 0; j < EMB; ++j) {
            float a = acc[j];
            a = fmaf(v.x, w[0 * EMB + j], a);
            a = fmaf(v.y, w[1 * EMB + j], a);
            a = fmaf(v.z, w[2 * EMB + j], a);
            a = fmaf(v.w, w[3 * EMB + j], a);
            acc[j] = a;
        }
    }
    float4* o = (float4*)(h + (size_t)n * HP);
    o[0] = make_float4(acc[0], acc[1], acc[2], acc[3]);
    o[1] = make_float4(acc[4], acc[5], acc[6], 0.0f);
}

__global__ void __launch_bounds__(256, 2)
k_fused(const void* __restrict__ eidx, int* __restrict__ T, int* __restrict__ gpk,
        int* __restrict__ base, int* __restrict__ btot,
        const float* __restrict__ x, const float* __restrict__ W,
        float* __restrict__ h, const float* __restrict__ b_in,
        float* __restrict__ outn, const void* __restrict__ batch,
        const float* __restrict__ W_out, const float* __restrict__ b_out,
        float* __restrict__ out)
{
    cg::grid_group grid = cg::this_grid();
    __shared__ SMemU sm;
    const int b = (int)blockIdx.x, t = (int)threadIdx.x;

    // ---- edge-index dtype detect (block-local; int64 -> odd words all 0) ----
    if (t == 0) sm.bins[0] = 0;
    __syncthreads();
    {
        const int* w32 = (const int*)eidx;
        int any = 0;
        for (int k2 = t; k2 < 2048; k2 += 256)
            if (w32[2 * k2 + 1] != 0) any = 1;
        if (any) atomicOr(&sm.bins[0], 1);
    }
    __syncthreads();
    const int is32 = sm.bins[0];
    __syncthreads();

    // ---- P1: per-block bucket histogram + matmul half A (even blocks) ------
    for (int k = t; k < NBUCK; k += 256) sm.bins[k] = 0;
    __syncthreads();
    {
        long long e0 = (long long)b * TILE_A;
        for (int i = t; i < TILE_A; i += 256) {
            int d = load_idx(eidx, (long long)N_EDGES + e0 + i, is32);
            atomicAdd(&sm.bins[d >> BSH], 1);
        }
    }
    __syncthreads();
    for (int k = t; k < NBUCK; k += 256) T[b * NBUCK + k] = sm.bins[k];
    if ((b & 1) == 0 && (b >> 1) < 196) mm_span((b >> 1) * 256, x, W, h);
    grid.sync();

    // ---- P2a: bucket totals (column reduce of T) ---------------------------
    if (b < NBUCK) {
        int v = T[t * NBUCK + b] + T[(t + 256) * NBUCK + b];
        for (int o = 32; o > 0; o >>= 1) v += __shfl_down(v, o);
        if ((t & 63) == 0) sm.sc.wsum[t >> 6] = v;
        __syncthreads();
        if (t == 0)
            btot[b] = sm.sc.wsum[0] + sm.sc.wsum[1] + sm.sc.wsum[2] + sm.sc.wsum[3];
    }
    grid.sync();

    // ---- P2b: bucket base prefix + column scan of T (rewrite as starts) ----
    if (b < NBUCK) {
        int v = 0;
        for (int j = t; j < b; j += 256) v += btot[j];
        for (int o = 32; o > 0; o >>= 1) v += __shfl_down(v, o);
        if ((t & 63) == 0) sm.sc.wsum[t >> 6] = v;
        __syncthreads();
        if (t == 0) {
            int a = sm.sc.wsum[0] + sm.sc.wsum[1] + sm.sc.wsum[2] + sm.sc.wsum[3];
            sm.sc.bkv = a;
            base[b] = a;
        }
        __syncthreads();
        int bk = sm.sc.bkv;
        int c0 = T[(2 * t) * NBUCK + b];
        int c1 = T[(2 * t + 1) * NBUCK + b];
        int pr = c0 + c1;
        int inc = pr;
        for (int o = 1; o < 64; o <<= 1) {
            int u = __shfl_up(inc, o);
            if ((t & 63) >= o) inc += u;
        }
        sm.sc.pair[t] = inc;                 // wave-inclusive pair sums
        __syncthreads();
        int add = 0, w = t >> 6;
        if (w >= 1) add += sm.sc.pair[63];
        if (w >= 2) add += sm.sc.pair[127];
        if (w >= 3) add += sm.sc.pair[191];
        int excl = inc + add - pr;           // exclusive over 512 rows
        T[(2 * t) * NBUCK + b]     = bk + excl;
        T[(2 * t + 1) * NBUCK + b] = bk + excl + c0;
    }
    grid.sync();

    // ---- P3: partition scatter + matmul half B (odd blocks) ----------------
    for (int k = t; k < NBUCK; k += 256) sm.cur[k] = T[b * NBUCK + k];
    __syncthreads();
    {
        long long e0 = (long long)b * TILE_A;
        for (int i = t; i < TILE_A; i += 256) {
            int src = load_idx(eidx, e0 + i, is32);
            int d   = load_idx(eidx, (long long)N_EDGES + e0 + i, is32);
            int slot = atomicAdd(&sm.cur[d >> BSH], 1);
            gpk[slot] = src | ((d & DMASK) << 17);   // src<2^17, dstlocal 8b
        }
    }
    if ((b & 1) == 1 && (b >> 1) < 195) mm_span((196 + (b >> 1)) * 256, x, W, h);
    grid.sync();

    // ---- P4: per-bucket node histogram + scale own h by dinv ---------------
    int s0 = 0, len = 0;
    if (b < NBUCK) {
        s0 = base[b];
        len = btot[b];
        if (len > SEGCAP) len = SEGCAP;      // statistically unreachable
        sm.gg.bin[t] = 0;
        __syncthreads();
        for (int i = t; i < len; i += 256)
            atomicAdd(&sm.gg.bin[(gpk[s0 + i] >> 17) & DMASK], 1);
        __syncthreads();
        int node = (b << BSH) + t;
        if (node < N_NODES) {
            float di = rsqrtf((float)sm.gg.bin[t] + 1.0f);
            float4* hp = (float4*)(h + (size_t)node * HP);
            float4 a = hp[0], c = hp[1];
            hp[0] = make_float4(a.x * di, a.y * di, a.z * di, a.w * di);
            hp[1] = make_float4(c.x * di, c.y * di, c.z * di, 0.0f);
        }
    }
    grid.sync();

    // ---- P5: regroup edges in LDS + gather + fused epilogue ----------------
    if (b < NBUCK) {
        int v = sm.gg.bin[t];                // bin persists from P4
        int inc = v;
        for (int o = 1; o < 64; o <<= 1) {
            int u = __shfl_up(inc, o);
            if ((t & 63) >= o) inc += u;
        }
        sm.gg.tmp[t] = inc;
        sm.gg.curs[t] = 0;
        __syncthreads();
        int add = 0, w = t >> 6;
        if (w >= 1) add += sm.gg.tmp[63];
        if (w >= 2) add += sm.gg.tmp[127];
        if (w >= 3) add += sm.gg.tmp[191];
        sm.gg.loff[t] = inc + add - v;       // exclusive within bucket
        __syncthreads();
        for (int i = t; i < len; i += 256) {
            int p = gpk[s0 + i];
            int dl = (p >> 17) & DMASK;
            int r = atomicAdd(&sm.gg.curs[dl], 1);
            sm.gg.stage[sm.gg.loff[dl] + r] = p & 0x1FFFF;
        }
        __syncthreads();
        const float4* h4 = (const float4*)h;
        int q = t & 3;
#pragma unroll
        for (int g4 = 0; g4 < 4; ++g4) {
            int nl = (t >> 2) + g4 * 64;
            int node = (b << BSH) + nl;
            if (node < N_NODES) {
                int o = sm.gg.loff[nl], c = sm.gg.bin[nl];
                float acc[EMB];
#pragma unroll
                for (int j = 0; j < EMB; ++j) acc[j] = 0.0f;
                for (int kk = q; kk < c; kk += 4) {
                    int s = sm.gg.stage[o + kk];
                    float4 a4 = h4[(size_t)s * 2];
                    float4 c4 = h4[(size_t)s * 2 + 1];
                    acc[0] += a4.x; acc[1] += a4.y; acc[2] += a4.z; acc[3] += a4.w;
                    acc[4] += c4.x; acc[5] += c4.y; acc[6] += c4.z;
                }
                if (q == 0) {               // self loop (hs[node], pre-scaled)
                    float4 a4 = h4[(size_t)node * 2];
                    float4 c4 = h4[(size_t)node * 2 + 1];
                    acc[0] += a4.x; acc[1] += a4.y; acc[2] += a4.z; acc[3] += a4.w;
                    acc[4] += c4.x; acc[5] += c4.y; acc[6] += c4.z;
                }
#pragma unroll
                for (int j = 0; j < EMB; ++j) {
                    acc[j] += __shfl_xor(acc[j], 1);
                    acc[j] += __shfl_xor(acc[j], 2);
                }
                float di = rsqrtf((float)c + 1.0f);
                int j0 = 2 * q;
                float v0 = fmaxf(fmaf(di, acc[j0], b_in[j0]), 0.0f);
                float v1 = (j0 + 1 < EMB)
                         ? fmaxf(fmaf(di, acc[j0 + 1], b_in[j0 + 1]), 0.0f) : 0.0f;
                ((float2*)(outn + (size_t)node * HP))[q] = make_float2(v0, v1);
            }
        }
    }
    grid.sync();

    // ---- P6: per-graph mean pool + logits + softmax ------------------------
    if (t == 0) sm.pool.bflag = 0;
    __syncthreads();
    {
        const int* w32 = (const int*)batch;   // sample late entries (sorted)
        int any = 0;
        for (int k2 = 1024 + t; k2 < 2048; k2 += 256)
            if (w32[2 * k2 + 1] != 0) any = 1;
        if (any) atomicOr(&sm.pool.bflag, 1);
    }
    __syncthreads();
    const int bis32 = sm.pool.bflag;

    for (int g = b; g < N_GRAPHS; g += GRID) {
        int n0, n1;
        {
            int lo = 0, hi = N_NODES;
            while (lo < hi) { int m = (lo + hi) >> 1; if (load_idx(batch, m, bis32) < g) lo = m + 1; else hi = m; }
            n0 = lo;
            hi = N_NODES;
            while (lo < hi) { int m = (lo + hi) >> 1; if (load_idx(batch, m, bis32) < g + 1) lo = m + 1; else hi = m; }
            n1 = lo;
        }
        float acc[EMB];
#pragma unroll
        for (int j = 0; j < EMB; ++j) acc[j] = 0.0f;
        for (int n = n0 + t; n < n1; n += 256) {
            const float4* o4 = (const float4*)(outn + (size_t)n * HP);
            float4 a = o4[0], c = o4[1];
            acc[0] += a.x; acc[1] += a.y; acc[2] += a.z; acc[3] += a.w;
            acc[4] += c.x; acc[5] += c.y; acc[6] += c.z;
        }
#pragma unroll
        for (int j = 0; j < EMB; ++j) {
            float v = acc[j];
            for (int o = 32; o > 0; o >>= 1) v += __shfl_down(v, o);
            acc[j] = v;
        }
        int wave = t >> 6, lane = t & 63;
        if (lane == 0) {
#pragma unroll
            for (int j = 0; j < EMB; ++j) sm.pool.sred[wave][j] = acc[j];
        }
        __syncthreads();
        if (t == 0) {
            float sums[EMB];
#pragma unroll
            for (int j = 0; j < EMB; ++j)
                sums[j] = sm.pool.sred[0][j] + sm.pool.sred[1][j]
                        + sm.pool.sred[2][j] + sm.pool.sred[3][j];
            float inv = 1.0f / fmaxf((float)(n1 - n0), 1.0f);
            float logit[N_CLASSES];
            float mx = -1e30f;
#pragma unroll
            for (int c = 0; c < N_CLASSES; ++c) {
                float l = b_out[c];
#pragma unroll
                for (int j = 0; j < EMB; ++j)
                    l = fmaf(sums[j] * inv, W_out[j * N_CLASSES + c], l);
                logit[c] = l;
                mx = fmaxf(mx, l);
            }
            float se = 0.0f;
#pragma unroll
            for (int c = 0; c < N_CLASSES; ++c) {
                logit[c] = expf(logit[c] - mx);
                se += logit[c];
            }
            float is = 1.0f / se;
#pragma unroll
            for (int c = 0; c < N_CLASSES; ++c)
                out[(size_t)g * N_CLASSES + c] = logit[c] * is;
        }
        __syncthreads();   // protect sred before next graph
    }
}

extern "C" void kernel_launch(void* const* d_in, const int* in_sizes, int n_in,
                              void* d_out, int out_size, void* d_ws, size_t ws_size,
                              hipStream_t stream) {
    const float* x     = (const float*)d_in[0];
    const void*  eidx  = d_in[1];
    const void*  batch = d_in[2];
    const float* W_in  = (const float*)d_in[3];
    const float* b_in  = (const float*)d_in[4];
    // d_in[5], d_in[6] = W_conv1, b_conv1 — dead code in reference.
    const float* W_out = (const float*)d_in[7];
    const float* b_out = (const float*)d_in[8];
    float* out = (float*)d_out;

    // ---- workspace layout (~20.2 MB); all float4 regions 16B-aligned -------
    int*   gpk  = (int*)d_ws;                    // 3,200,000 ints
    int*   T    = gpk + N_EDGES;                 // 512*391 = 200,192 ints
    float* h    = (float*)(T + GRID * NBUCK);    // 800,000 floats (byte off 13,600,768)
    float* outn = h + (size_t)N_NODES * HP;      // 800,000 floats
    int*   btot = (int*)(outn + (size_t)N_NODES * HP);  // NBUCK
    int*   base = btot + NBUCK;                  // NBUCK

    void* kargs[] = {
        (void*)&eidx, (void*)&T, (void*)&gpk, (void*)&base, (void*)&btot,
        (void*)&x, (void*)&W_in, (void*)&h, (void*)&b_in, (void*)&outn,
        (void*)&batch, (void*)&W_out, (void*)&b_out, (void*)&out
    };
    hipLaunchCooperativeKernel((void*)k_fused, dim3(GRID), dim3(256),
                               kargs, 0, stream);
}

// Round 13
// 163.981 us; speedup vs baseline: 3.4347x; 3.4347x over previous
//
#include <hip/hip_runtime.h>

#define N_NODES   100000
#define N_EDGES   3200000
#define N_GRAPHS  1000
#define FEAT      512
#define EMB       7
#define HP        8      // padded per-node feature stride
#define N_CLASSES 10

#define BSH       8      // 256 nodes per bucket
#define DMASK     255
#define NBUCK     391    // ceil(100000/256)
#define TCOLS     392    // NBUCK+1 (row-end sentinel)
#define NB_A      512    // sort blocks
#define TILE_A    6250   // 512*6250 == 3.2M exactly
#define SEGCAP    9216   // bucket total: mean 8192, +11 sigma
#define MMF       391    // matmul filler blocks appended to k_sortblk grid

__device__ __forceinline__ int load_idx(const void* p, long long i, int is32) {
    if (is32) return ((const int*)p)[i];
    return (int)((const long long*)p)[i];
}

// ---- self-detect int32 vs int64 storage of edge_index ----------------------
__device__ int edge_is32(const void* p) {
    __shared__ int sflag;
    if (threadIdx.x == 0) sflag = 0;
    __syncthreads();
    const int* w = (const int*)p;
    int any = 0;
    for (int k = threadIdx.x; k < 2048; k += blockDim.x)
        if (w[2 * k + 1] != 0) any = 1;
    if (any) atomicOr(&sflag, 1);
    __syncthreads();
    return sflag;
}

// batch is sorted from graph 0; sample entries 1024..2047 (nonzero if int32).
__device__ int batch_is32(const void* p) {
    __shared__ int sflag;
    if (threadIdx.x == 0) sflag = 0;
    __syncthreads();
    const int* w = (const int*)p;
    int any = 0;
    for (int k = 1024 + threadIdx.x; k < 2048; k += blockDim.x)
        if (w[2 * k + 1] != 0) any = 1;
    if (any) atomicOr(&sflag, 1);
    __syncthreads();
    return sflag;
}

// ---- matmul tile: h[n] = x[n] @ W_in (UNSCALED), 256 nodes/block -----------
__device__ void mm_span(int nbase, const float* __restrict__ x,
                        const float* __restrict__ W, float* __restrict__ h) {
    int n = nbase + (int)threadIdx.x;
    if (n >= N_NODES) return;
    const float4* xr = (const float4*)(x + (size_t)n * FEAT);
    float acc[EMB];
#pragma unroll
    for (int j = 0; j < EMB; ++j) acc[j] = 0.0f;
#pragma unroll 4
    for (int k4 = 0; k4 < FEAT / 4; ++k4) {
        float4 v = xr[k4];
        const float* w = W + k4 * 4 * EMB;
#pragma unroll
        for (int j = 0; j < EMB; ++j) {
            float a = acc[j];
            a = fmaf(v.x, w[0 * EMB + j], a);
            a = fmaf(v.y, w[1 * EMB + j], a);
            a = fmaf(v.z, w[2 * EMB + j], a);
            a = fmaf(v.w, w[3 * EMB + j], a);
            acc[j] = a;
        }
    }
    float4* o = (float4*)(h + (size_t)n * HP);
    o[0] = make_float4(acc[0], acc[1], acc[2], acc[3]);
    o[1] = make_float4(acc[4], acc[5], acc[6], 0.0f);
}

// ---- pass 1: block-local counting sort by bucket (+ matmul filler) ---------
// Block b sorts its 6250 edges by dst-bucket in LDS, writes them COALESCED to
// gpk[b*6250 ..), and writes absolute run starts T[b][k] (T[b][NBUCK] = end).
__global__ void k_sortblk(const void* __restrict__ eidx, int* __restrict__ T,
                          int* __restrict__ gpk, const float* __restrict__ x,
                          const float* __restrict__ W, float* __restrict__ h) {
    if (blockIdx.x >= NB_A) { mm_span(((int)blockIdx.x - NB_A) * 256, x, W, h); return; }
    __shared__ int stage[TILE_A];        // 25 KB
    __shared__ int bins[NBUCK];          // counts -> local starts
    __shared__ int cur[NBUCK];
    __shared__ int pairv[256];
    __shared__ int wsum[4];
    int is32 = edge_is32(eidx);
    const int b = (int)blockIdx.x, t = (int)threadIdx.x;
    for (int k = t; k < NBUCK; k += 256) bins[k] = 0;
    __syncthreads();
    long long e0 = (long long)b * TILE_A;
    // pass A: histogram (dst only)
    for (int i = t; i < TILE_A; i += 256) {
        int d = load_idx(eidx, (long long)N_EDGES + e0 + i, is32);
        atomicAdd(&bins[d >> BSH], 1);
    }
    __syncthreads();
    // exclusive scan of 391 bins (pair-per-thread, wave scan + cross-wave)
    int c0 = (2 * t     < NBUCK) ? bins[2 * t]     : 0;
    int c1 = (2 * t + 1 < NBUCK) ? bins[2 * t + 1] : 0;
    int pr = c0 + c1;
    int inc = pr;
    for (int o = 1; o < 64; o <<= 1) {
        int u = __shfl_up(inc, o);
        if ((t & 63) >= o) inc += u;
    }
    if ((t & 63) == 63) wsum[t >> 6] = inc;
    pairv[t] = inc;
    __syncthreads();
    int add = 0, wv = t >> 6;
    if (wv >= 1) add += wsum[0];
    if (wv >= 2) add += wsum[1];
    if (wv >= 3) add += wsum[2];
    int excl = inc + add - pr;
    __syncthreads();
    if (2 * t     < NBUCK) { bins[2 * t]     = excl;      cur[2 * t]     = excl; }
    if (2 * t + 1 < NBUCK) { bins[2 * t + 1] = excl + c0; cur[2 * t + 1] = excl + c0; }
    __syncthreads();
    // write T row (absolute starts)
    for (int k = t; k < NBUCK; k += 256)
        T[b * TCOLS + k] = b * TILE_A + bins[k];
    if (t == 0) T[b * TCOLS + NBUCK] = (b + 1) * TILE_A;
    // pass B: re-read edges, scatter into LDS stage by bucket
    for (int i = t; i < TILE_A; i += 256) {
        int src = load_idx(eidx, e0 + i, is32);
        int d   = load_idx(eidx, (long long)N_EDGES + e0 + i, is32);
        int slot = atomicAdd(&cur[d >> BSH], 1);
        stage[slot] = src | ((d & DMASK) << 17);   // src<2^17, dstlocal 8 bits
    }
    __syncthreads();
    // coalesced write-out
    for (int i = t; i < TILE_A; i += 256)
        gpk[b * TILE_A + i] = stage[i];
}

// ---- run-table loader: rstart[512] abs starts, rst[513] local prefix -------
__device__ int load_runs(const int* __restrict__ T, int k,
                         int* rstart, int* rst, int* pairv, int* wsum) {
    const int t = (int)threadIdx.x;
    int b0 = 2 * t, b1 = 2 * t + 1;
    int s0 = T[b0 * TCOLS + k], e0 = T[b0 * TCOLS + k + 1];
    int s1 = T[b1 * TCOLS + k], e1 = T[b1 * TCOLS + k + 1];
    rstart[b0] = s0; rstart[b1] = s1;
    int c0 = e0 - s0, c1 = e1 - s1;
    int pr = c0 + c1;
    int inc = pr;
    for (int o = 1; o < 64; o <<= 1) {
        int u = __shfl_up(inc, o);
        if ((t & 63) >= o) inc += u;
    }
    if ((t & 63) == 63) wsum[t >> 6] = inc;
    __syncthreads();
    int add = 0, wv = t >> 6;
    if (wv >= 1) add += wsum[0];
    if (wv >= 2) add += wsum[1];
    if (wv >= 3) add += wsum[2];
    int excl = inc + add - pr;
    rst[b0] = excl;
    rst[b1] = excl + c0;
    if (t == 255) rst[512] = excl + pr;   // total
    __syncthreads();
    return rst[512];
}

__device__ __forceinline__ int run_of(const int* rst, int i) {
    int lo = 0, hi = 512;
    while (lo + 1 < hi) { int m = (lo + hi) >> 1; if (rst[m] <= i) lo = m; else hi = m; }
    return lo;
}

// ---- pass 2: per-node degree count + pre-scale h by dinv -------------------
__global__ void k_nodecnt(const int* __restrict__ T, const int* __restrict__ gpk,
                          int* __restrict__ cnt, float* __restrict__ h) {
    __shared__ int rstart[512], rst[513], pairv[256], wsum[4];
    __shared__ int bin[256];
    const int k = (int)blockIdx.x, t = (int)threadIdx.x;
    bin[t] = 0;
    int total = load_runs(T, k, rstart, rst, pairv, wsum);
    __syncthreads();
    for (int i = t; i < total; i += 256) {
        int b = run_of(rst, i);
        int p = gpk[rstart[b] + (i - rst[b])];
        atomicAdd(&bin[(p >> 17) & DMASK], 1);
    }
    __syncthreads();
    int node = (k << BSH) + t;
    if (node < N_NODES) {
        int c = bin[t];
        cnt[node] = c;
        float di = rsqrtf((float)c + 1.0f);
        float4* hp = (float4*)(h + (size_t)node * HP);
        float4 a = hp[0], cc = hp[1];
        hp[0] = make_float4(a.x * di, a.y * di, a.z * di, a.w * di);
        hp[1] = make_float4(cc.x * di, cc.y * di, cc.z * di, 0.0f);
    }
}

// ---- pass 3: regroup runs in LDS by node + gather + fused epilogue ---------
// out[n] = relu(dinv[n]*(hs[n] + sum_{s->n} hs[s]) + b_in), hs pre-scaled.
__global__ void k_ggather(const int* __restrict__ T, const int* __restrict__ gpk,
                          const int* __restrict__ cnt, const float* __restrict__ h,
                          const float* __restrict__ b_in, float* __restrict__ outn) {
    __shared__ int stage[SEGCAP];        // 36 KB
    __shared__ int rstart[512], rst[513], pairv[256], wsum[4];
    __shared__ int bin[256], loff[256], curs[256];
    const int k = (int)blockIdx.x, t = (int)threadIdx.x;
    int total = load_runs(T, k, rstart, rst, pairv, wsum);
    int len = (total > SEGCAP) ? SEGCAP : total;   // statistically unreachable
    {
        int node = (k << BSH) + t;
        bin[t] = (node < N_NODES) ? cnt[node] : 0;
        curs[t] = 0;
    }
    __syncthreads();
    // 4-wave inclusive scan of 256 bins -> loff (exclusive)
    {
        int v = bin[t];
        int inc = v;
        for (int o = 1; o < 64; o <<= 1) {
            int u = __shfl_up(inc, o);
            if ((t & 63) >= o) inc += u;
        }
        pairv[t] = inc;
        __syncthreads();
        int add = 0, wv = t >> 6;
        if (wv >= 1) add += pairv[63];
        if (wv >= 2) add += pairv[127];
        if (wv >= 3) add += pairv[191];
        loff[t] = inc + add - v;
    }
    __syncthreads();
    // scatter runs -> LDS stage grouped by node
    for (int i = t; i < len; i += 256) {
        int b = run_of(rst, i);
        int p = gpk[rstart[b] + (i - rst[b])];
        int dl = (p >> 17) & DMASK;
        int r = atomicAdd(&curs[dl], 1);
        stage[loff[dl] + r] = p & 0x1FFFF;
    }
    __syncthreads();
    // gather: 4 lanes/node, 4 rounds of 64 nodes
    const float4* h4 = (const float4*)h;
    int q = t & 3;
#pragma unroll
    for (int g4 = 0; g4 < 4; ++g4) {
        int nl = (t >> 2) + g4 * 64;
        int node = (k << BSH) + nl;
        if (node < N_NODES) {
            int o = loff[nl], c = bin[nl];
            float acc[EMB];
#pragma unroll
            for (int j = 0; j < EMB; ++j) acc[j] = 0.0f;
            for (int kk = q; kk < c; kk += 4) {
                int s = stage[o + kk];
                float4 a4 = h4[(size_t)s * 2];
                float4 c4 = h4[(size_t)s * 2 + 1];
                acc[0] += a4.x; acc[1] += a4.y; acc[2] += a4.z; acc[3] += a4.w;
                acc[4] += c4.x; acc[5] += c4.y; acc[6] += c4.z;
            }
            if (q == 0) {                 // self loop (hs[node], pre-scaled)
                float4 a4 = h4[(size_t)node * 2];
                float4 c4 = h4[(size_t)node * 2 + 1];
                acc[0] += a4.x; acc[1] += a4.y; acc[2] += a4.z; acc[3] += a4.w;
                acc[4] += c4.x; acc[5] += c4.y; acc[6] += c4.z;
            }
#pragma unroll
            for (int j = 0; j < EMB; ++j) {
                acc[j] += __shfl_xor(acc[j], 1);
                acc[j] += __shfl_xor(acc[j], 2);
            }
            float di = rsqrtf((float)c + 1.0f);
            int j0 = 2 * q;
            float v0 = fmaxf(fmaf(di, acc[j0], b_in[j0]), 0.0f);
            float v1 = (j0 + 1 < EMB)
                     ? fmaxf(fmaf(di, acc[j0 + 1], b_in[j0 + 1]), 0.0f) : 0.0f;
            ((float2*)(outn + (size_t)node * HP))[q] = make_float2(v0, v1);
        }
    }
}

// ---- per-graph mean pool + logits + softmax (fused binary search) ----------
__global__ void k_pool(const float* __restrict__ outn, const void* __restrict__ batch,
                       const float* __restrict__ W_out, const float* __restrict__ b_out,
                       float* __restrict__ out) {
    int g = blockIdx.x;
    int is32 = batch_is32(batch);
    int n0, n1;
    {
        int lo = 0, hi = N_NODES;
        while (lo < hi) { int m = (lo + hi) >> 1; if (load_idx(batch, m, is32) < g) lo = m + 1; else hi = m; }
        n0 = lo;
        hi = N_NODES;
        while (lo < hi) { int m = (lo + hi) >> 1; if (load_idx(batch, m, is32) < g + 1) lo = m + 1; else hi = m; }
        n1 = lo;
    }
    float acc[EMB];
#pragma unroll
    for (int j = 0; j < EMB; ++j) acc[j] = 0.0f;
    for (int n = n0 + (int)threadIdx.x; n < n1; n += (int)blockDim.x) {
        const float4* o4 = (const float4*)(outn + (size_t)n * HP);
        float4 a = o4[0], b = o4[1];
        acc[0] += a.x; acc[1] += a.y; acc[2] += a.z; acc[3] += a.w;
        acc[4] += b.x; acc[5] += b.y; acc[6] += b.z;
    }
#pragma unroll
    for (int j = 0; j < EMB; ++j) {
        float v = acc[j];
        for (int o = 32; o > 0; o >>= 1) v += __shfl_down(v, o);
        acc[j] = v;
    }
    __shared__ float sred[4][EMB];
    int wave = threadIdx.x >> 6, lane = threadIdx.x & 63;
    if (lane == 0) {
#pragma unroll
        for (int j = 0; j < EMB; ++j) sred[wave][j] = acc[j];
    }
    __syncthreads();
    if (threadIdx.x == 0) {
        float sums[EMB];
#pragma unroll
        for (int j = 0; j < EMB; ++j)
            sums[j] = sred[0][j] + sred[1][j] + sred[2][j] + sred[3][j];
        float inv = 1.0f / fmaxf((float)(n1 - n0), 1.0f);
        float logit[N_CLASSES];
        float mx = -1e30f;
#pragma unroll
        for (int c = 0; c < N_CLASSES; ++c) {
            float l = b_out[c];
#pragma unroll
            for (int j = 0; j < EMB; ++j)
                l = fmaf(sums[j] * inv, W_out[j * N_CLASSES + c], l);
            logit[c] = l;
            mx = fmaxf(mx, l);
        }
        float se = 0.0f;
#pragma unroll
        for (int c = 0; c < N_CLASSES; ++c) {
            logit[c] = expf(logit[c] - mx);
            se += logit[c];
        }
        float is = 1.0f / se;
#pragma unroll
        for (int c = 0; c < N_CLASSES; ++c)
            out[(size_t)g * N_CLASSES + c] = logit[c] * is;
    }
}

extern "C" void kernel_launch(void* const* d_in, const int* in_sizes, int n_in,
                              void* d_out, int out_size, void* d_ws, size_t ws_size,
                              hipStream_t stream) {
    const float* x     = (const float*)d_in[0];
    const void*  eidx  = d_in[1];
    const void*  batch = d_in[2];
    const float* W_in  = (const float*)d_in[3];
    const float* b_in  = (const float*)d_in[4];
    // d_in[5], d_in[6] = W_conv1, b_conv1 — dead code in reference.
    const float* W_out = (const float*)d_in[7];
    const float* b_out = (const float*)d_in[8];
    float* out = (float*)d_out;

    // ---- workspace layout (~20.5 MB); h/outn 16B-aligned -------------------
    int*   gpk  = (int*)d_ws;                    // 3,200,000 ints
    int*   T    = gpk + N_EDGES;                 // 512*392 = 200,704 ints
    int*   cnt  = T + NB_A * TCOLS;              // 100,000 ints
    float* h    = (float*)(cnt + N_NODES);       // 800,000 f (byte off 14,002,816)
    float* outn = h + (size_t)N_NODES * HP;      // 800,000 f

    const int B = 256;
    k_sortblk<<<NB_A + MMF, B, 0, stream>>>(eidx, T, gpk, x, W_in, h);
    k_nodecnt<<<NBUCK, B, 0, stream>>>(T, gpk, cnt, h);
    k_ggather<<<NBUCK, B, 0, stream>>>(T, gpk, cnt, h, b_in, outn);
    k_pool   <<<N_GRAPHS, B, 0, stream>>>(outn, batch, W_out, b_out, out);
}